// Round 8
// baseline (204.979 us; speedup 1.0000x reference)
//
#include <hip/hip_runtime.h>
#include <math.h>

#define T_TOK 4096
#define C_DIM 256
#define EPSF  1e-5f
// hd^-0.5 * log2(e): folded into q-rows of the qkv weights -> scores in log2 domain
#define SC_QL (0.17677669529663687f * 1.4426950408889634f)

typedef short  bf16x8  __attribute__((ext_vector_type(8)));
typedef float  f32x4   __attribute__((ext_vector_type(4)));
typedef ushort ushort8 __attribute__((ext_vector_type(8)));

__device__ __forceinline__ short f2bf(float f) {
    unsigned u = __builtin_bit_cast(unsigned, f);
    unsigned r = (u + 0x7FFFu + ((u >> 16) & 1u)) >> 16;
    return (short)r;
}
__device__ __forceinline__ float bf2f(ushort u) {
    return __builtin_bit_cast(float, ((unsigned)u) << 16);
}
__device__ __forceinline__ unsigned pk_bf16(float a, float b) {
    const unsigned ua = __builtin_bit_cast(unsigned, a) + 0x8000u;
    const unsigned ub = __builtin_bit_cast(unsigned, b) + 0x8000u;
    return __builtin_amdgcn_perm(ub, ua, 0x07060302u);
}
template <int CTRL>
__device__ __forceinline__ float dppf(float x) {
    return __builtin_bit_cast(float,
        __builtin_amdgcn_mov_dpp(__builtin_bit_cast(int, x), CTRL, 0xF, 0xF, true));
}
__device__ __forceinline__ float rowsum16(float x) {
    x += dppf<0xB1>(x);
    x += dppf<0x4E>(x);
    x += dppf<0x141>(x);
    x += dppf<0x140>(x);
    return x;
}
#define MFMA16(a, b, c) __builtin_amdgcn_mfma_f32_16x16x32_bf16(a, b, c, 0, 0, 0)

// ---------------------------------------------------------------------------
// prep: [0,896) weights f32->bf16 arena with LN folding:
//   wqkv scaled by ln1_g[k] (and SC_QL for q-rows); wff1 scaled by ln2_g[k].
// [896,1920): BN(eval)+transpose x[c][t] -> tin bf16 [t][c].
// [1920,2368): u/d vectors: u=sum_k g_k W[c,k], d=sum_k beta_k W[c,k]+bias_c
//   (rows 0..767 = qkv w/ ln1 + SC_QL on q; rows 768..1791 = ff1 w/ ln2).
// ---------------------------------------------------------------------------
__global__ __launch_bounds__(256) void prep_kernel(
    const float* __restrict__ w_in, const float* __restrict__ w_qkv,
    const float* __restrict__ w_ap, const float* __restrict__ w_ff1,
    const float* __restrict__ w_ff2, const float* __restrict__ w_out,
    const float* __restrict__ b_qkv, const float* __restrict__ b_ff1,
    const float* __restrict__ ln1_g, const float* __restrict__ ln1_b,
    const float* __restrict__ ln2_g, const float* __restrict__ ln2_b,
    ushort* __restrict__ wbuf, float* __restrict__ u_all, float* __restrict__ d_all,
    const float* __restrict__ x, const float* __restrict__ gamma,
    const float* __restrict__ beta, const float* __restrict__ mean,
    const float* __restrict__ var, ushort* __restrict__ tin)
{
    __shared__ float tile[32][33];
    if (blockIdx.x < 896) {
        const int gid = blockIdx.x * 256 + threadIdx.x;
        const int e0 = gid * 4;
        const float* src; int off;
        float4 sc = {1.f, 1.f, 1.f, 1.f};
        if (e0 < 65536)       { src = w_in;  off = e0; }
        else if (e0 < 262144) {
            src = w_qkv; off = e0 - 65536;
            const int k = off & 255;
            sc = *(const float4*)(ln1_g + k);
            if (off < 65536) { sc.x *= SC_QL; sc.y *= SC_QL; sc.z *= SC_QL; sc.w *= SC_QL; }
        }
        else if (e0 < 327680) { src = w_ap;  off = e0 - 262144; }
        else if (e0 < 589824) {
            src = w_ff1; off = e0 - 327680;
            sc = *(const float4*)(ln2_g + (off & 255));
        }
        else if (e0 < 851968) { src = w_ff2; off = e0 - 589824; }
        else                  { src = w_out; off = e0 - 851968; }
        const float4 v = *(const float4*)(src + off);
        ushort4 o;
        o.x = (ushort)f2bf(v.x * sc.x); o.y = (ushort)f2bf(v.y * sc.y);
        o.z = (ushort)f2bf(v.z * sc.z); o.w = (ushort)f2bf(v.w * sc.w);
        *(ushort4*)(wbuf + e0) = o;
    } else if (blockIdx.x < 1920) {
        const int bidx = blockIdx.x - 896;
        const int t0 = (bidx & 127) * 32, c0 = (bidx >> 7) * 32;
        const int tx = threadIdx.x & 31, ty = threadIdx.x >> 5;
#pragma unroll
        for (int i = 0; i < 32; i += 8) {
            const int c = c0 + ty + i;
            const float a = rsqrtf(var[c] + EPSF) * gamma[c];
            const float d = beta[c] - mean[c] * a;
            tile[ty + i][tx] = x[c * T_TOK + t0 + tx] * a + d;
        }
        __syncthreads();
#pragma unroll
        for (int i = 0; i < 32; i += 8) {
            const int t = t0 + ty + i;
            tin[t * C_DIM + c0 + tx] = (ushort)f2bf(tile[tx][ty + i]);
        }
    } else {
        const int row = (blockIdx.x - 1920) * 4 + (threadIdx.x >> 6);
        const int lane = threadIdx.x & 63;
        const float* W; const float* gv; const float* bv; float bias; float qs = 1.f;
        if (row < 768) {
            W = w_qkv + (size_t)row * 256; gv = ln1_g; bv = ln1_b; bias = b_qkv[row];
            if (row < 256) qs = SC_QL;
        } else {
            const int r2 = row - 768;
            W = w_ff1 + (size_t)r2 * 256; gv = ln2_g; bv = ln2_b; bias = b_ff1[r2];
        }
        const float4 w4 = *(const float4*)(W + lane * 4);
        const float4 g4 = *(const float4*)(gv + lane * 4);
        const float4 b4 = *(const float4*)(bv + lane * 4);
        float su = w4.x * g4.x + w4.y * g4.y + w4.z * g4.z + w4.w * g4.w;
        float sd = w4.x * b4.x + w4.y * b4.y + w4.z * b4.z + w4.w * b4.w;
#pragma unroll
        for (int off = 32; off > 0; off >>= 1) {
            su += __shfl_xor(su, off);
            sd += __shfl_xor(sd, off);
        }
        if (lane == 0) {
            u_all[row] = qs * su;
            d_all[row] = qs * (sd + bias);
        }
    }
}

// ---------------------------------------------------------------------------
// Fused pre-attention: proj_in + (LN1 folded) QKV. grid 256, block 1024.
// GEMM2 runs on raw v; LN applied as per-row affine in the epilogue.
// Outputs: tok0 f32, lnstats (mu,rs per token), qkv bf16.
// ---------------------------------------------------------------------------
__global__ __launch_bounds__(1024) void fused_pre(
    const ushort* __restrict__ tin, const ushort* __restrict__ wb_in,
    const float* __restrict__ b_in, const ushort* __restrict__ wb_qkv,
    const float* __restrict__ u_all, const float* __restrict__ d_all,
    float* __restrict__ tok0, float* __restrict__ lnstats,
    ushort* __restrict__ qkvb)
{
    __shared__ ushort Atile[16 * 264];
    __shared__ ushort Vt[16 * 264];
    __shared__ float  red[16][16][2];
    const int t0 = blockIdx.x * 16;
    const int tid = threadIdx.x, wv = tid >> 6, lane = tid & 63;
    const int c = lane & 15, g = lane >> 4;

    // prefetch GEMM1 (proj_in) weight frags: barrier-independent
    bf16x8 w1[8];
#pragma unroll
    for (int kc = 0; kc < 8; ++kc)
        w1[kc] = *(const bf16x8*)(wb_in + (size_t)(wv * 16 + c) * 256 + kc * 32 + g * 8);

    {   // stage 16x256 bf16 input tile
        const int r = tid >> 6, c0 = (tid & 63) * 4;
        *(ushort4*)&Atile[r * 264 + c0] = *(const ushort4*)(tin + (size_t)(t0 + r) * 256 + c0);
    }
    __syncthreads();

    // ---- GEMM1: proj_in, one frag/wave ----
    f32x4 acc1 = {};
#pragma unroll
    for (int kc = 0; kc < 8; ++kc) {
        const bf16x8 af = *(const bf16x8*)&Atile[c * 264 + kc * 32 + g * 8];
        acc1 = MFMA16(af, w1[kc], acc1);
    }
    const int colp = wv * 16 + c;
    float vs[4];
    {
        const float bb = b_in[colp];
        float s1[4], s2[4];
#pragma unroll
        for (int rr = 0; rr < 4; ++rr) {
            const float v = acc1[rr] + bb;
            vs[rr] = v; s1[rr] = v; s2[rr] = v * v;
            tok0[(size_t)(t0 + 4 * g + rr) * 256 + colp] = v;
            Vt[(4 * g + rr) * 264 + colp] = (ushort)f2bf(v);
        }
#pragma unroll
        for (int rr = 0; rr < 4; ++rr) { s1[rr] = rowsum16(s1[rr]); s2[rr] = rowsum16(s2[rr]); }
        if (c == 0) {
#pragma unroll
            for (int rr = 0; rr < 4; ++rr) {
                red[wv][4 * g + rr][0] = s1[rr];
                red[wv][4 * g + rr][1] = s2[rr];
            }
        }
    }
    __syncthreads();

    // cross-wave LN reduce (32 threads) overlaps GEMM2 MFMAs of other waves
    if (tid < 32) {
        const int row = tid >> 1, j = tid & 1;
        float s = 0.f;
#pragma unroll
        for (int w = 0; w < 16; ++w) s += red[w][row][j];
        red[0][row][j] = s;
    }

    // ---- GEMM2: QKV on raw v with LN-folded weights, 3 frags/wave ----
    f32x4 acc2[3] = {};
#pragma unroll
    for (int kc = 0; kc < 8; ++kc) {
        const bf16x8 af = *(const bf16x8*)&Vt[c * 264 + kc * 32 + g * 8];
#pragma unroll
        for (int nf = 0; nf < 3; ++nf) {
            const bf16x8 bfv = *(const bf16x8*)(wb_qkv +
                (size_t)(wv * 48 + nf * 16 + c) * 256 + kc * 32 + g * 8);
            acc2[nf] = MFMA16(af, bfv, acc2[nf]);
        }
    }
    __syncthreads();

    float mu[4], rs[4];
#pragma unroll
    for (int rr = 0; rr < 4; ++rr) {
        const int row = 4 * g + rr;
        mu[rr] = red[0][row][0] * (1.0f / 256.0f);
        const float var = red[0][row][1] * (1.0f / 256.0f) - mu[rr] * mu[rr];
        rs[rr] = rsqrtf(var + EPSF);
    }
    if (wv == 0 && c == 0) {
#pragma unroll
        for (int rr = 0; rr < 4; ++rr) {
            lnstats[(size_t)(t0 + 4 * g + rr) * 2 + 0] = mu[rr];
            lnstats[(size_t)(t0 + 4 * g + rr) * 2 + 1] = rs[rr];
        }
    }
#pragma unroll
    for (int nf = 0; nf < 3; ++nf) {
        const int col = wv * 48 + nf * 16 + c;
        const float u = u_all[col], d = d_all[col];
#pragma unroll
        for (int rr = 0; rr < 4; ++rr) {
            const float q = rs[rr] * (acc2[nf][rr] - mu[rr] * u) + d;
            qkvb[(size_t)(t0 + 4 * g + rr) * 768 + col] = (ushort)f2bf(q);
        }
    }
}

// ---------------------------------------------------------------------------
// Flash attention, bf16 MFMA, no-max exp2 softmax, split-K over 4 quarters.
// grid=(T/64, HEADS, 4), block=256 (4 waves), 5 blocks/CU (LDS 27.6KB).
// Ps stride 34: b32 writes (4-way), b64 frag reads (4-way; was 8-way b128).
// ---------------------------------------------------------------------------
#define KS   40
#define VTS  72
#define PS_W 34

__global__ __launch_bounds__(256) void attn_mfma(
    const ushort* __restrict__ qkv, ushort* __restrict__ opart,
    float* __restrict__ lpart)
{
    const int h    = blockIdx.y;
    const int q0   = blockIdx.x << 6;
    const int half = blockIdx.z;
    const int tid  = threadIdx.x;
    const int wv   = tid >> 6, lane = tid & 63;
    const int c    = lane & 15, g = lane >> 4;

    __shared__ ushort Ks[2][64 * KS];
    __shared__ ushort Vt[2][32 * VTS];
    __shared__ float  Ps[4][16 * PS_W];

    const bf16x8 qf = *(const bf16x8*)(qkv + (size_t)(q0 + wv * 16 + c) * 768 + h * 32 + g * 8);

    bf16x8 ones;
#pragma unroll
    for (int i = 0; i < 8; ++i) ones[i] = (short)0x3F80;

    f32x4 oacc0 = {0.f, 0.f, 0.f, 0.f};
    f32x4 oacc1 = {0.f, 0.f, 0.f, 0.f};
    f32x4 oaccl = {0.f, 0.f, 0.f, 0.f};

    const int kr = tid >> 2, kc = (tid & 3) * 8;
    const int vp = tid & 31, vd = (tid >> 5) * 4;
    const ushort* kbase = qkv + 256 + h * 32;
    const ushort* vbase = qkv + 512 + h * 32;

    const int kt0 = half * 16, kt1 = kt0 + 16;
    ushort8 kpre  = *(const ushort8*)(kbase + ((size_t)kt0 * 64 + kr) * 768 + kc);
    ushort4 vpre0 = *(const ushort4*)(vbase + ((size_t)kt0 * 64 + 2 * vp) * 768 + vd);
    ushort4 vpre1 = *(const ushort4*)(vbase + ((size_t)kt0 * 64 + 2 * vp + 1) * 768 + vd);

    int p = 0;
    for (int kt = kt0; kt < kt1; ++kt) {
        *(ushort8*)&Ks[p][kr * KS + kc] = kpre;
        {
            unsigned* vtp = (unsigned*)&Vt[p][0];
            vtp[(vd + 0) * (VTS / 2) + vp] = (unsigned)vpre0.x | ((unsigned)vpre1.x << 16);
            vtp[(vd + 1) * (VTS / 2) + vp] = (unsigned)vpre0.y | ((unsigned)vpre1.y << 16);
            vtp[(vd + 2) * (VTS / 2) + vp] = (unsigned)vpre0.z | ((unsigned)vpre1.z << 16);
            vtp[(vd + 3) * (VTS / 2) + vp] = (unsigned)vpre0.w | ((unsigned)vpre1.w << 16);
        }
        __syncthreads();
        if (kt + 1 < kt1) {
            const size_t t0 = (size_t)(kt + 1) * 64;
            kpre  = *(const ushort8*)(kbase + (t0 + kr) * 768 + kc);
            vpre0 = *(const ushort4*)(vbase + (t0 + 2 * vp) * 768 + vd);
            vpre1 = *(const ushort4*)(vbase + (t0 + 2 * vp + 1) * 768 + vd);
        }

        const ushort* ks = &Ks[p][0];
        const ushort* vt = &Vt[p][0];
        const f32x4 zz = {0.f, 0.f, 0.f, 0.f};
        const bf16x8 k0 = *(const bf16x8*)&ks[(0 * 16 + c) * KS + g * 8];
        const bf16x8 k1 = *(const bf16x8*)&ks[(1 * 16 + c) * KS + g * 8];
        const bf16x8 k2 = *(const bf16x8*)&ks[(2 * 16 + c) * KS + g * 8];
        const bf16x8 k3 = *(const bf16x8*)&ks[(3 * 16 + c) * KS + g * 8];
        const f32x4 s0 = MFMA16(k0, qf, zz);
        const f32x4 s1 = MFMA16(k1, qf, zz);
        const f32x4 s2 = MFMA16(k2, qf, zz);
        const f32x4 s3 = MFMA16(k3, qf, zz);

        float* prow = &Ps[wv][c * PS_W];
        {
            const float e00 = __builtin_amdgcn_exp2f(s0[0]), e01 = __builtin_amdgcn_exp2f(s0[1]);
            const float e02 = __builtin_amdgcn_exp2f(s0[2]), e03 = __builtin_amdgcn_exp2f(s0[3]);
            const float e10 = __builtin_amdgcn_exp2f(s1[0]), e11 = __builtin_amdgcn_exp2f(s1[1]);
            const float e12 = __builtin_amdgcn_exp2f(s1[2]), e13 = __builtin_amdgcn_exp2f(s1[3]);
            const float e20 = __builtin_amdgcn_exp2f(s2[0]), e21 = __builtin_amdgcn_exp2f(s2[1]);
            const float e22 = __builtin_amdgcn_exp2f(s2[2]), e23 = __builtin_amdgcn_exp2f(s2[3]);
            const float e30 = __builtin_amdgcn_exp2f(s3[0]), e31 = __builtin_amdgcn_exp2f(s3[1]);
            const float e32 = __builtin_amdgcn_exp2f(s3[2]), e33 = __builtin_amdgcn_exp2f(s3[3]);
            prow[0 * 8 + 2 * g + 0] = __builtin_bit_cast(float, pk_bf16(e00, e01));
            prow[0 * 8 + 2 * g + 1] = __builtin_bit_cast(float, pk_bf16(e02, e03));
            prow[1 * 8 + 2 * g + 0] = __builtin_bit_cast(float, pk_bf16(e10, e11));
            prow[1 * 8 + 2 * g + 1] = __builtin_bit_cast(float, pk_bf16(e12, e13));
            prow[2 * 8 + 2 * g + 0] = __builtin_bit_cast(float, pk_bf16(e20, e21));
            prow[2 * 8 + 2 * g + 1] = __builtin_bit_cast(float, pk_bf16(e22, e23));
            prow[3 * 8 + 2 * g + 0] = __builtin_bit_cast(float, pk_bf16(e30, e31));
            prow[3 * 8 + 2 * g + 1] = __builtin_bit_cast(float, pk_bf16(e32, e33));
        }
#pragma unroll
        for (int ch = 0; ch < 2; ++ch) {
            const float2 pA = *(const float2*)&prow[ch * 16 + 4 * g];
            const float2 pB = *(const float2*)&prow[ch * 16 + 4 * g + 2];
            unsigned pw[4];
            pw[0] = __builtin_bit_cast(unsigned, pA.x);
            pw[1] = __builtin_bit_cast(unsigned, pA.y);
            pw[2] = __builtin_bit_cast(unsigned, pB.x);
            pw[3] = __builtin_bit_cast(unsigned, pB.y);
            const bf16x8 pf = *(const bf16x8*)pw;
            const bf16x8 v0 = *(const bf16x8*)&vt[(c)      * VTS + ch * 32 + g * 8];
            const bf16x8 v1 = *(const bf16x8*)&vt[(16 + c) * VTS + ch * 32 + g * 8];
            oacc0 = MFMA16(pf, v0, oacc0);
            oacc1 = MFMA16(pf, v1, oacc1);
            oaccl = MFMA16(pf, ones, oaccl);
        }
        p ^= 1;
        __syncthreads();
    }

    {
        ushort* op = opart + (size_t)half * (1u << 20) + (size_t)(q0 + wv * 16) * 256 + h * 32;
#pragma unroll
        for (int rr = 0; rr < 4; ++rr) {
            op[(4 * g + rr) * 256 + c]      = (ushort)f2bf(oacc0[rr]);
            op[(4 * g + rr) * 256 + 16 + c] = (ushort)f2bf(oacc1[rr]);
        }
        if (c == 0) {
#pragma unroll
            for (int rr = 0; rr < 4; ++rr)
                lpart[(size_t)(q0 + wv * 16 + 4 * g + rr) * 32 + half * 8 + h] = oaccl[rr];
        }
    }
}

// ---------------------------------------------------------------------------
// Fused mid: combine 4 O-partials + attn-proj + residuals (+y recomputed from
// tok0 & lnstats) + (LN2 folded) FF1 + gelu. grid 256, block 1024.
// ---------------------------------------------------------------------------
__global__ __launch_bounds__(1024) void fused_mid(
    const ushort* __restrict__ opart, const float* __restrict__ lpart,
    const ushort* __restrict__ wb_ap, const float* __restrict__ b_ap,
    const float* __restrict__ tok0, const float* __restrict__ lnstats,
    const float* __restrict__ ln1_g, const float* __restrict__ ln1_b,
    const ushort* __restrict__ wb_ff1, const float* __restrict__ u_all,
    const float* __restrict__ d_all, float* __restrict__ tok1,
    ushort* __restrict__ zbuf)
{
    __shared__ ushort Otile[16 * 264];
    __shared__ ushort Vt[16 * 264];
    __shared__ float  red[16][16][2];
    const int t0 = blockIdx.x * 16;
    const int tid = threadIdx.x, wv = tid >> 6, lane = tid & 63;
    const int c = lane & 15, g = lane >> 4;

    // prefetch GEMM1 (attn-proj) weight frags
    bf16x8 w1[8];
#pragma unroll
    for (int kc = 0; kc < 8; ++kc)
        w1[kc] = *(const bf16x8*)(wb_ap + (size_t)(wv * 16 + c) * 256 + kc * 32 + g * 8);

    {   // combine 4 O partials
        const int r = tid >> 6, c0 = (tid & 63) * 4;
        const int h = (tid & 63) >> 3;
        const float* lp = lpart + (size_t)(t0 + r) * 32;
        const float inv = 1.0f / (lp[h] + lp[8 + h] + lp[16 + h] + lp[24 + h]);
        const size_t base = (size_t)(t0 + r) * 256 + c0;
        const ushort4 a0 = *(const ushort4*)(opart + base);
        const ushort4 a1 = *(const ushort4*)(opart + (1u << 20) + base);
        const ushort4 a2 = *(const ushort4*)(opart + (2u << 20) + base);
        const ushort4 a3 = *(const ushort4*)(opart + (3u << 20) + base);
        unsigned w[2];
        w[0] = pk_bf16((bf2f(a0.x) + bf2f(a1.x) + bf2f(a2.x) + bf2f(a3.x)) * inv,
                       (bf2f(a0.y) + bf2f(a1.y) + bf2f(a2.y) + bf2f(a3.y)) * inv);
        w[1] = pk_bf16((bf2f(a0.z) + bf2f(a1.z) + bf2f(a2.z) + bf2f(a3.z)) * inv,
                       (bf2f(a0.w) + bf2f(a1.w) + bf2f(a2.w) + bf2f(a3.w)) * inv);
        *(ushort4*)&Otile[r * 264 + c0] = *(ushort4*)w;
    }
    __syncthreads();

    // ---- GEMM1: attn-proj, one frag/wave ----
    f32x4 acc1 = {};
#pragma unroll
    for (int kc = 0; kc < 8; ++kc) {
        const bf16x8 af = *(const bf16x8*)&Otile[c * 264 + kc * 32 + g * 8];
        acc1 = MFMA16(af, w1[kc], acc1);
    }
    const int colp = wv * 16 + c;
    {
        const float bb = b_ap[colp];
        const float g1 = ln1_g[colp], b1 = ln1_b[colp];
        float s1[4], s2[4];
#pragma unroll
        for (int rr = 0; rr < 4; ++rr) {
            const int row = t0 + 4 * g + rr;
            const size_t idx = (size_t)row * 256 + colp;
            const float t0v = tok0[idx];
            const float mu1 = lnstats[(size_t)row * 2 + 0];
            const float rs1 = lnstats[(size_t)row * 2 + 1];
            const float y = (t0v - mu1) * rs1 * g1 + b1;
            const float v = acc1[rr] + bb + y + t0v;
            s1[rr] = v; s2[rr] = v * v;
            tok1[idx] = v;
            Vt[(4 * g + rr) * 264 + colp] = (ushort)f2bf(v);
        }
#pragma unroll
        for (int rr = 0; rr < 4; ++rr) { s1[rr] = rowsum16(s1[rr]); s2[rr] = rowsum16(s2[rr]); }
        if (c == 0) {
#pragma unroll
            for (int rr = 0; rr < 4; ++rr) {
                red[wv][4 * g + rr][0] = s1[rr];
                red[wv][4 * g + rr][1] = s2[rr];
            }
        }
    }
    __syncthreads();

    if (tid < 32) {
        const int row = tid >> 1, j = tid & 1;
        float s = 0.f;
#pragma unroll
        for (int w = 0; w < 16; ++w) s += red[w][row][j];
        red[0][row][j] = s;
    }

    // ---- GEMM2: FF1 on raw v with LN2-folded weights, 4 frags/wave ----
    f32x4 acc2[4] = {};
#pragma unroll
    for (int kc = 0; kc < 8; ++kc) {
        const bf16x8 af = *(const bf16x8*)&Vt[c * 264 + kc * 32 + g * 8];
#pragma unroll
        for (int nf = 0; nf < 4; ++nf) {
            const bf16x8 bfv = *(const bf16x8*)(wb_ff1 +
                (size_t)(wv * 64 + nf * 16 + c) * 256 + kc * 32 + g * 8);
            acc2[nf] = MFMA16(af, bfv, acc2[nf]);
        }
    }
    __syncthreads();

    float mu[4], rs[4];
#pragma unroll
    for (int rr = 0; rr < 4; ++rr) {
        const int row = 4 * g + rr;
        mu[rr] = red[0][row][0] * (1.0f / 256.0f);
        const float var = red[0][row][1] * (1.0f / 256.0f) - mu[rr] * mu[rr];
        rs[rr] = rsqrtf(var + EPSF);
    }
#pragma unroll
    for (int nf = 0; nf < 4; ++nf) {
        const int col = wv * 64 + nf * 16 + c;
        const float u = u_all[768 + col], d = d_all[768 + col];
#pragma unroll
        for (int rr = 0; rr < 4; ++rr) {
            float v = rs[rr] * (acc2[nf][rr] - mu[rr] * u) + d;
            v = 0.5f * v * (1.0f + erff(v * 0.70710678118654752f));
            zbuf[(size_t)(t0 + 4 * g + rr) * 1024 + col] = (ushort)f2bf(v);
        }
    }
}

// ---------------------------------------------------------------------------
// Fused post: FF2 + residual + proj_out + outer residual. grid 256, block 1024.
// ---------------------------------------------------------------------------
__global__ __launch_bounds__(1024) void fused_post(
    const ushort* __restrict__ zbuf, const ushort* __restrict__ wb_ff2,
    const float* __restrict__ b_ff2, const float* __restrict__ tok1,
    const ushort* __restrict__ wb_out, const float* __restrict__ b_out,
    const float* __restrict__ x, float* __restrict__ out)
{
    __shared__ ushort Ztile[16 * 1032];
    __shared__ ushort T2tile[16 * 264];
    const int t0 = blockIdx.x * 16;
    const int tid = threadIdx.x, wv = tid >> 6, lane = tid & 63;
    const int c = lane & 15, g = lane >> 4;

    // prefetch first 8 FF2 weight frags (of 32)
    bf16x8 w2[8];
#pragma unroll
    for (int kc = 0; kc < 8; ++kc)
        w2[kc] = *(const bf16x8*)(wb_ff2 + (size_t)(wv * 16 + c) * 1024 + kc * 32 + g * 8);

    {   // stage zbuf tile 16x1024 bf16
        const int r = tid >> 6, c0 = (tid & 63) * 16;
        *(ushort8*)&Ztile[r * 1032 + c0] =
            *(const ushort8*)(zbuf + (size_t)(t0 + r) * 1024 + c0);
        *(ushort8*)&Ztile[r * 1032 + c0 + 8] =
            *(const ushort8*)(zbuf + (size_t)(t0 + r) * 1024 + c0 + 8);
    }
    __syncthreads();

    // ---- FF2: one frag/wave, K=1024 ----
    f32x4 accf = {};
#pragma unroll
    for (int kc = 0; kc < 8; ++kc) {
        const bf16x8 af = *(const bf16x8*)&Ztile[c * 1032 + kc * 32 + g * 8];
        accf = MFMA16(af, w2[kc], accf);
    }
#pragma unroll
    for (int kc = 8; kc < 32; ++kc) {
        const bf16x8 af = *(const bf16x8*)&Ztile[c * 1032 + kc * 32 + g * 8];
        const bf16x8 bfv = *(const bf16x8*)(wb_ff2 +
            (size_t)(wv * 16 + c) * 1024 + kc * 32 + g * 8);
        accf = MFMA16(af, bfv, accf);
    }
    {
        const int col = wv * 16 + c;
        const float bb = b_ff2[col];
#pragma unroll
        for (int rr = 0; rr < 4; ++rr) {
            const size_t idx = (size_t)(t0 + 4 * g + rr) * 256 + col;
            const float v = accf[rr] + bb + tok1[idx];
            T2tile[(4 * g + rr) * 264 + col] = (ushort)f2bf(v);
        }
    }
    __syncthreads();

    // ---- proj_out: wave w -> out rows [16w,16w+16) ----
    f32x4 acco = {};
#pragma unroll
    for (int kc = 0; kc < 8; ++kc) {
        const bf16x8 bfr = *(const bf16x8*)&T2tile[c * 264 + kc * 32 + g * 8];
        const bf16x8 afr = *(const bf16x8*)(wb_out +
            (size_t)(wv * 16 + c) * 256 + kc * 32 + g * 8);
        acco = MFMA16(afr, bfr, acco);
    }
#pragma unroll
    for (int rr = 0; rr < 4; ++rr) {
        const int och = wv * 16 + 4 * g + rr;
        const size_t idx = (size_t)och * T_TOK + t0 + c;
        out[idx] = acco[rr] + b_out[och] + x[idx];
    }
}

// ---------------------------------------------------------------------------
extern "C" void kernel_launch(void* const* d_in, const int* in_sizes, int n_in,
                              void* d_out, int out_size, void* d_ws, size_t ws_size,
                              hipStream_t stream)
{
    const float* x     = (const float*)d_in[0];
    const float* bn_g  = (const float*)d_in[1];
    const float* bn_b  = (const float*)d_in[2];
    const float* bn_m  = (const float*)d_in[3];
    const float* bn_v  = (const float*)d_in[4];
    const float* w_in  = (const float*)d_in[5];
    const float* b_in  = (const float*)d_in[6];
    const float* ln1_g = (const float*)d_in[7];
    const float* ln1_b = (const float*)d_in[8];
    const float* w_qkv = (const float*)d_in[9];
    const float* b_qkv = (const float*)d_in[10];
    const float* w_ap  = (const float*)d_in[11];
    const float* b_ap  = (const float*)d_in[12];
    const float* ln2_g = (const float*)d_in[13];
    const float* ln2_b = (const float*)d_in[14];
    const float* w_ff1 = (const float*)d_in[15];
    const float* b_ff1 = (const float*)d_in[16];
    const float* w_ff2 = (const float*)d_in[17];
    const float* b_ff2 = (const float*)d_in[18];
    const float* w_out = (const float*)d_in[19];
    const float* b_out = (const float*)d_in[20];
    float* out = (float*)d_out;
    float* ws  = (float*)d_ws;

    const size_t MF = 1u << 20;   // 1M f32 = 4 MB
    float*  tok0   = ws;                                   // [0,1M)
    float*  tok1   = ws + MF;                              // [1M,2M)
    float*  lnst   = ws + 2 * MF;                          // [2M, +8K floats)
    ushort* qkv_bf = (ushort*)(ws + 3 * MF);               // [3M,4.5M)
    ushort* tin_bf = (ushort*)(ws + 4 * MF + MF / 2);      // [4.5M,5M)
    ushort* opart  = tin_bf;                               // reuse: 4x1M ushorts [4.5M,6.5M)
    ushort* zbuf   = (ushort*)(ws + 6 * MF + MF / 2);      // [6.5M,8.5M)
    float*  lpart  = ws + 8 * MF + MF / 2;                 // [8.5M, +128K floats)
    ushort* wbuf   = (ushort*)(ws + 8 * MF + MF / 2 + 131072);  // weight arena
    const ushort* wb_in  = wbuf;
    const ushort* wb_qkv = wbuf + 65536;
    const ushort* wb_ap  = wbuf + 262144;
    const ushort* wb_ff1 = wbuf + 327680;
    const ushort* wb_ff2 = wbuf + 589824;
    const ushort* wb_out = wbuf + 851968;
    float* u_all = (float*)(wbuf + 917504);                // 1792 f32
    float* d_all = u_all + 1792;                           // 1792 f32

    prep_kernel<<<2368, 256, 0, stream>>>(
        w_in, w_qkv, w_ap, w_ff1, w_ff2, w_out,
        b_qkv, b_ff1, ln1_g, ln1_b, ln2_g, ln2_b,
        wbuf, u_all, d_all,
        x, bn_g, bn_b, bn_m, bn_v, tin_bf);
    fused_pre<<<256, 1024, 0, stream>>>(tin_bf, wb_in, b_in, wb_qkv,
                                        u_all, d_all, tok0, lnst, qkv_bf);
    attn_mfma<<<dim3(64, 8, 4), 256, 0, stream>>>(qkv_bf, opart, lpart);
    fused_mid<<<256, 1024, 0, stream>>>(opart, lpart, wb_ap, b_ap, tok0, lnst,
                                        ln1_g, ln1_b, wb_ff1, u_all, d_all,
                                        tok1, zbuf);
    fused_post<<<256, 1024, 0, stream>>>(zbuf, wb_ff2, b_ff2, tok1, wb_out, b_out,
                                         x, out);
}